// Round 6
// baseline (262.573 us; speedup 1.0000x reference)
//
#include <hip/hip_runtime.h>
#include <hip/hip_bf16.h>

#define N_NODES 200000
#define KDIM 27
#define C_IN 32
#define C_OUT 32
#define NPART 4
#define PSIZE 50000              // N_NODES / NPART, 3.2 MB bf16 per partition
#define NS (NPART * KDIM)        // 108 pipeline stages
#define PF 4                     // fragment prefetch depth (ring slots)

typedef __bf16 bf16x8 __attribute__((ext_vector_type(8)));
typedef float floatx4 __attribute__((ext_vector_type(4)));
typedef float float4_t __attribute__((ext_vector_type(4)));

__device__ __forceinline__ void load_frag16(bf16x8& dst, const __bf16* addr) {
    asm volatile("global_load_dwordx4 %0, %1, off" : "=v"(dst) : "v"(addr));
}

// vmcnt at top of stage j: steady state has 4 stages x 4 loads in flight;
// retire the oldest stage's 4 -> wait 12. Tail shrinks as issues stop.
constexpr int wt_top(int j) {
    return (j <= NS - 4) ? 12 : (j == NS - 3 ? 8 : (j == NS - 2 ? 4 : 0));
}

// ---------------- Kernel 1: fused convert (fp32->bf16 + sentinel) + pack ---
__global__ __launch_bounds__(256) void prep_kernel(
    const float* __restrict__ data, const float* __restrict__ w,
    __bf16* __restrict__ data_bf, __bf16* __restrict__ wpack) {
    const int b = blockIdx.x;
    const int tid = threadIdx.x;
    if (b < 3125) {                       // convert: 3125*256*8 = 6.4M elems
        int i = b * 256 + tid;
        const float4_t* s = (const float4_t*)data;
        float4_t v0 = __builtin_nontemporal_load(&s[2 * i]);
        float4_t v1 = __builtin_nontemporal_load(&s[2 * i + 1]);
        bf16x8 o;
        o[0] = (__bf16)v0[0]; o[1] = (__bf16)v0[1];
        o[2] = (__bf16)v0[2]; o[3] = (__bf16)v0[3];
        o[4] = (__bf16)v1[0]; o[5] = (__bf16)v1[1];
        o[6] = (__bf16)v1[2]; o[7] = (__bf16)v1[3];
        ((bf16x8*)data_bf)[i] = o;
        if (b == 0 && tid < 4) {          // zero sentinel node N_NODES
            bf16x8 z;
#pragma unroll
            for (int t = 0; t < 8; ++t) z[t] = (__bf16)0.0f;
            ((bf16x8*)data_bf)[N_NODES * 4 + tid] = z;
        }
    } else {                              // pack weights: 108 blocks
        int id = (b - 3125) * 256 + tid;
        int j = id & 7;
        int l = (id >> 3) & 63;
        int t = (id >> 9) & 1;
        int kk = id >> 10;
        int c = ((l >> 4) << 3) + j;
        int o = t * 16 + (l & 15);
        wpack[id] = (__bf16)w[(kk * C_IN + c) * C_OUT + o];
    }
}

// ---------------- Kernel 2: partitioned asm-pipelined gather-GEMM ----------
// All 5 prior rounds show dur = (FETCH+WRITE)/3.2 TB/s -> L2-miss-traffic
// bound. NPART=4 passes keep each pass's gather source (3.2 MB) resident in
// the 4 MB per-XCD L2; out-of-partition taps read the zero sentinel (exact:
// fp32 acc + 0.0). neigh staged once in LDS (13.8 KB) to avoid 4x re-reads.
// Pipeline: 108 macro-expanded stages, asm loads, counted vmcnt (never 0
// until drain), sched_barrier(0) per stage.

#define ISSUE_FRAGS(SLOT, P, KK, RAW0, RAW1)                                    \
    {                                                                           \
        unsigned u0_ = ((unsigned)((RAW0) - (P) * PSIZE) < (unsigned)PSIZE)     \
                           ? (unsigned)(RAW0) : (unsigned)N_NODES;              \
        unsigned u1_ = ((unsigned)((RAW1) - (P) * PSIZE) < (unsigned)PSIZE)     \
                           ? (unsigned)(RAW1) : (unsigned)N_NODES;              \
        load_frag16(a0b[SLOT], dch + ((size_t)u0_ << 5));                       \
        load_frag16(a1b[SLOT], dch + ((size_t)u1_ << 5));                       \
        load_frag16(b0b[SLOT], wlane + (KK) * 1024);                            \
        load_frag16(b1b[SLOT], wlane + (KK) * 1024 + 512);                      \
    }

#define STAGE(J)                                                                \
    {                                                                           \
        constexpr int J_ = (J);                                                 \
        asm volatile("s_waitcnt vmcnt(%0)" ::"n"(wt_top(J_)) : "memory");       \
        __builtin_amdgcn_sched_barrier(0);                                      \
        constexpr int s_ = J_ % PF;                                             \
        acc00 = __builtin_amdgcn_mfma_f32_16x16x32_bf16(a0b[s_], b0b[s_], acc00, 0, 0, 0); \
        acc01 = __builtin_amdgcn_mfma_f32_16x16x32_bf16(a0b[s_], b1b[s_], acc01, 0, 0, 0); \
        acc10 = __builtin_amdgcn_mfma_f32_16x16x32_bf16(a1b[s_], b0b[s_], acc10, 0, 0, 0); \
        acc11 = __builtin_amdgcn_mfma_f32_16x16x32_bf16(a1b[s_], b1b[s_], acc11, 0, 0, 0); \
        if constexpr (J_ + PF < NS) {                                           \
            constexpr int T_ = J_ + PF;                                         \
            constexpr int P_ = T_ / KDIM;                                       \
            constexpr int K_ = T_ % KDIM;                                       \
            int raw0_ = rp0[J_ & 1];                                            \
            int raw1_ = rp1[J_ & 1];                                            \
            ISSUE_FRAGS(s_, P_, K_, raw0_, raw1_);                              \
            if constexpr (J_ + 6 < NS) {                                        \
                rp0[J_ & 1] = nlds[lA0 + (J_ + 6) % KDIM];                      \
                rp1[J_ & 1] = nlds[lA1 + (J_ + 6) % KDIM];                      \
            }                                                                   \
        }                                                                       \
    }

#define S4(a) STAGE(a) STAGE((a) + 1) STAGE((a) + 2) STAGE((a) + 3)

__global__ __launch_bounds__(256, 3) void octconv_main_kernel(
    const int* __restrict__ neigh, const __bf16* __restrict__ data_bf,
    const __bf16* __restrict__ wpack, float* __restrict__ out) {
    __shared__ int nlds[128 * KDIM];      // 13824 B: this block's neigh slab

    const int tid  = threadIdx.x;
    const int wave = tid >> 6;
    const int lane = tid & 63;
    const int r16  = lane & 15;
    const int half = lane >> 4;           // 0..3 (k-block of the A fragment)
    const int cb   = half << 3;           // channel base (8 channels / group)
    const int node_base = (blockIdx.x * 4 + wave) * 32;

    // stage neigh -> LDS, coalesced, once (saves 3x global re-reads)
    {
        const long long gbase = (long long)blockIdx.x * 128 * KDIM;
        const long long gmax  = (long long)N_NODES * KDIM;
#pragma unroll
        for (int t = 0; t < 14; ++t) {
            int g = t * 256 + tid;
            if (g < 128 * KDIM) {
                long long gg = gbase + g;
                nlds[g] = (gg < gmax) ? __builtin_nontemporal_load(&neigh[gg]) : -1;
            }
        }
    }
    __syncthreads();

    const int lA0 = (wave * 32 + r16) * KDIM;
    const int lA1 = lA0 + 16 * KDIM;
    const __bf16* dch   = data_bf + cb;
    const __bf16* wlane = wpack + (size_t)lane * 8;

    floatx4 acc00 = {0.f, 0.f, 0.f, 0.f};
    floatx4 acc01 = {0.f, 0.f, 0.f, 0.f};
    floatx4 acc10 = {0.f, 0.f, 0.f, 0.f};
    floatx4 acc11 = {0.f, 0.f, 0.f, 0.f};

    bf16x8 a0b[PF], a1b[PF], b0b[PF], b1b[PF];   // fragment ring
    int rp0[2], rp1[2];                          // idx-pair ring (2-stage lead)

    // prologue: frags for stages 0..3 (all pass 0, kk 0..3), prime idx ring
    {
        int q0, q1;
        q0 = nlds[lA0 + 0]; q1 = nlds[lA1 + 0]; ISSUE_FRAGS(0, 0, 0, q0, q1);
        q0 = nlds[lA0 + 1]; q1 = nlds[lA1 + 1]; ISSUE_FRAGS(1, 0, 1, q0, q1);
        q0 = nlds[lA0 + 2]; q1 = nlds[lA1 + 2]; ISSUE_FRAGS(2, 0, 2, q0, q1);
        q0 = nlds[lA0 + 3]; q1 = nlds[lA1 + 3]; ISSUE_FRAGS(3, 0, 3, q0, q1);
    }
    rp0[0] = nlds[lA0 + 4]; rp1[0] = nlds[lA1 + 4];   // pair for stage 4
    rp0[1] = nlds[lA0 + 5]; rp1[1] = nlds[lA1 + 5];   // pair for stage 5

    S4(0)   S4(4)   S4(8)   S4(12)  S4(16)  S4(20)  S4(24)
    S4(28)  S4(32)  S4(36)  S4(40)  S4(44)  S4(48)  S4(52)
    S4(56)  S4(60)  S4(64)  S4(68)  S4(72)  S4(76)  S4(80)
    S4(84)  S4(88)  S4(92)  S4(96)  S4(100) S4(104)

#pragma unroll
    for (int r = 0; r < 4; ++r) {
        int row = half * 4 + r;
        int n0 = node_base + row;
        int n1 = n0 + 16;
        if (n0 < N_NODES) {
            __builtin_nontemporal_store(acc00[r], &out[n0 * C_OUT + r16]);
            __builtin_nontemporal_store(acc01[r], &out[n0 * C_OUT + 16 + r16]);
        }
        if (n1 < N_NODES) {
            __builtin_nontemporal_store(acc10[r], &out[n1 * C_OUT + r16]);
            __builtin_nontemporal_store(acc11[r], &out[n1 * C_OUT + 16 + r16]);
        }
    }
}

extern "C" void kernel_launch(void* const* d_in, const int* in_sizes, int n_in,
                              void* d_out, int out_size, void* d_ws, size_t ws_size,
                              hipStream_t stream) {
    const float* data    = (const float*)d_in[0];   // [N, C_IN] fp32
    const float* weights = (const float*)d_in[1];   // [K, C_IN, C_OUT] fp32
    const int*   neigh   = (const int*)d_in[2];     // [N, K] int32
    float*       out     = (float*)d_out;           // [N, C_OUT] fp32

    __bf16* data_bf = (__bf16*)d_ws;
    __bf16* wpack   = (__bf16*)((char*)d_ws + (size_t)(N_NODES + 1) * C_IN * sizeof(__bf16));

    // 1) fused convert + sentinel + weight pack (3125 + 108 blocks)
    hipLaunchKernelGGL(prep_kernel, dim3(3125 + 108), dim3(256), 0, stream,
                       data, weights, data_bf, wpack);
    // 2) partitioned gather + MFMA GEMM; 128 nodes per block
    int blocks = (N_NODES + 127) / 128;
    hipLaunchKernelGGL(octconv_main_kernel, dim3(blocks), dim3(256), 0, stream,
                       neigh, data_bf, wpack, out);
}